// Round 1
// baseline (662.217 us; speedup 1.0000x reference)
//
#include <hip/hip_runtime.h>
#include <hip/hip_bf16.h>

// Head: B=8, T=2048, D=1024, H=64, fp32 in/out.
// q=x@Wq, k=x@Wk, v=x@Wv; scores = (q k^T) * sqrt(T); causal; softmax; out = attn @ v.
#define BB 8
#define TT 2048
#define DD 1024
#define HH 64
#define NROWS (BB*TT)              // 16384 flattened rows
#define SCALE 45.25483399593904f   // sqrt(2048)

// ---------------------------------------------------------------------------
// Kernel A: QKV projection, fp32 SIMT.
// block = 256 threads (4 waves). Block handles 32 rows; each wave 8 rows.
// x tile staged in LDS per 128-wide D-chunk; W read from global (L2-resident).
// ---------------------------------------------------------------------------
__global__ __launch_bounds__(256) void qkv_kernel(
        const float* __restrict__ x,
        const float* __restrict__ Wq, const float* __restrict__ Wk,
        const float* __restrict__ Wv,
        float* __restrict__ Q, float* __restrict__ K, float* __restrict__ V) {
    __shared__ float xs[32 * 128];          // 16 KiB
    const int tid = threadIdx.x;
    const int h   = tid & 63;               // output column (H=64) == lane
    const int w   = tid >> 6;               // wave id 0..3
    const int row0 = blockIdx.x * 32;       // first flattened row of block

    float aq[8], ak[8], av[8];
    #pragma unroll
    for (int r = 0; r < 8; ++r) { aq[r] = 0.f; ak[r] = 0.f; av[r] = 0.f; }

    for (int c = 0; c < DD / 128; ++c) {
        __syncthreads();
        // cooperative stage: 32 rows x 128 cols fp32 = 1024 float4
        const float4* xg  = (const float4*)x + (size_t)row0 * 256 + c * 32;
        float4*       xs4 = (float4*)xs;
        #pragma unroll
        for (int p = 0; p < 4; ++p) {
            int i  = tid + p * 256;         // float4 index in tile
            int r  = i >> 5;                // row 0..31
            int c4 = i & 31;                // float4 col 0..31
            xs4[i] = xg[(size_t)r * 256 + c4];
        }
        __syncthreads();

        const float* wqp = Wq + (size_t)(c * 128) * HH + h;
        const float* wkp = Wk + (size_t)(c * 128) * HH + h;
        const float* wvp = Wv + (size_t)(c * 128) * HH + h;
        const float* xr  = xs + (w * 8) * 128;

        #pragma unroll 4
        for (int dd = 0; dd < 128; ++dd) {
            float wq = wqp[dd * HH];
            float wk = wkp[dd * HH];
            float wv = wvp[dd * HH];
            #pragma unroll
            for (int r = 0; r < 8; ++r) {
                float xv = xr[r * 128 + dd];        // wave-uniform: LDS broadcast
                aq[r] = fmaf(xv, wq, aq[r]);
                ak[r] = fmaf(xv, wk, ak[r]);
                av[r] = fmaf(xv, wv, av[r]);
            }
        }
    }

    const int rowb = row0 + w * 8;
    #pragma unroll
    for (int r = 0; r < 8; ++r) {
        size_t o = (size_t)(rowb + r) * HH + h;
        Q[o] = aq[r]; K[o] = ak[r]; V[o] = av[r];
    }
}

// ---------------------------------------------------------------------------
// Kernel B: causal flash attention, fp32 SIMT.
// block = 256 threads (4 waves), QT=32 query rows (8 per wave).
// Each query row is owned by 8 lanes (sub=0..7), each holding an 8-dim slice
// of q and of the output accumulator. K/V tiles (64 keys) staged in LDS.
// Scores: per-lane partial dots + 3-round butterfly shfl_xor -> every lane of
// the row group holds all 8 full scores, so PV needs no broadcast.
// ---------------------------------------------------------------------------
__global__ __launch_bounds__(256) void attn_kernel(
        const float* __restrict__ Q, const float* __restrict__ K,
        const float* __restrict__ V, float* __restrict__ out) {
    __shared__ float Ks[64 * 64];           // 16 KiB
    __shared__ float Vs[64 * 64];           // 16 KiB
    const int tid  = threadIdx.x;
    const int lane = tid & 63;
    const int w    = tid >> 6;              // wave 0..3
    const int sub  = lane & 7;              // dim-slice owner 0..7
    const int rloc = lane >> 3;             // row-in-wave 0..7
    const int b    = blockIdx.y;
    const int q0   = blockIdx.x * 32;       // first query row of block (in T)
    const int t    = q0 + w * 8 + rloc;     // this lane-group's query row

    const size_t rowQ = ((size_t)b * TT + t) * HH + sub * 8;
    float4 qa = *(const float4*)(Q + rowQ);
    float4 qb = *(const float4*)(Q + rowQ + 4);

    float4 accA = {0.f, 0.f, 0.f, 0.f};
    float4 accB = {0.f, 0.f, 0.f, 0.f};
    float  m = -1e30f, l = 0.f;

    const int numKT = (q0 + 31) / 64 + 1;   // key tiles covering keys <= q0+31

    for (int kt = 0; kt < numKT; ++kt) {
        __syncthreads();
        const float4* kg  = (const float4*)(K + ((size_t)b * TT + kt * 64) * HH);
        const float4* vg  = (const float4*)(V + ((size_t)b * TT + kt * 64) * HH);
        float4* ks4 = (float4*)Ks;
        float4* vs4 = (float4*)Vs;
        #pragma unroll
        for (int p = 0; p < 4; ++p) {
            int i = tid + p * 256;
            ks4[i] = kg[i];
            vs4[i] = vg[i];
        }
        __syncthreads();

        for (int j0 = 0; j0 < 64; j0 += 8) {
            // partial dots over this lane's 8-dim slice, 8 keys
            float s[8];
            #pragma unroll
            for (int kk = 0; kk < 8; ++kk) {
                const float4* kp = (const float4*)(Ks + (j0 + kk) * HH + sub * 8);
                float4 ka = kp[0], kb2 = kp[1];
                s[kk] = qa.x * ka.x + qa.y * ka.y + qa.z * ka.z + qa.w * ka.w
                      + qb.x * kb2.x + qb.y * kb2.y + qb.z * kb2.z + qb.w * kb2.w;
            }
            // butterfly all-reduce across the 8 sub-lanes (row group)
            #pragma unroll
            for (int kk = 0; kk < 8; ++kk) {
                s[kk] += __shfl_xor(s[kk], 1);
                s[kk] += __shfl_xor(s[kk], 2);
                s[kk] += __shfl_xor(s[kk], 4);
            }
            // scale + causal mask + tile max
            const int kbase = kt * 64 + j0;
            float pm = -1e30f;
            #pragma unroll
            for (int kk = 0; kk < 8; ++kk) {
                s[kk] = (kbase + kk <= t) ? s[kk] * SCALE : -1e30f;
                pm = fmaxf(pm, s[kk]);
            }
            // online-softmax rescale (uniform within the 8-lane row group)
            if (pm > m) {
                float es = __expf(m - pm);
                m = pm;
                l *= es;
                accA.x *= es; accA.y *= es; accA.z *= es; accA.w *= es;
                accB.x *= es; accB.y *= es; accB.z *= es; accB.w *= es;
            }
            float p[8], ps = 0.f;
            #pragma unroll
            for (int kk = 0; kk < 8; ++kk) {
                p[kk] = __expf(s[kk] - m);      // masked -> exp(-1e30 - m) = 0
                ps += p[kk];
            }
            l += ps;
            // PV accumulate on this lane's 8-dim slice
            #pragma unroll
            for (int kk = 0; kk < 8; ++kk) {
                const float4* vp = (const float4*)(Vs + (j0 + kk) * HH + sub * 8);
                float4 va = vp[0], vb = vp[1];
                accA.x = fmaf(p[kk], va.x, accA.x);
                accA.y = fmaf(p[kk], va.y, accA.y);
                accA.z = fmaf(p[kk], va.z, accA.z);
                accA.w = fmaf(p[kk], va.w, accA.w);
                accB.x = fmaf(p[kk], vb.x, accB.x);
                accB.y = fmaf(p[kk], vb.y, accB.y);
                accB.z = fmaf(p[kk], vb.z, accB.z);
                accB.w = fmaf(p[kk], vb.w, accB.w);
            }
        }
    }

    const float inv = 1.0f / l;
    float4 oA = {accA.x * inv, accA.y * inv, accA.z * inv, accA.w * inv};
    float4 oB = {accB.x * inv, accB.y * inv, accB.z * inv, accB.w * inv};
    *(float4*)(out + rowQ)     = oA;
    *(float4*)(out + rowQ + 4) = oB;
}

// ---------------------------------------------------------------------------
extern "C" void kernel_launch(void* const* d_in, const int* in_sizes, int n_in,
                              void* d_out, int out_size, void* d_ws, size_t ws_size,
                              hipStream_t stream) {
    const float* x  = (const float*)d_in[0];
    const float* Wq = (const float*)d_in[1];
    const float* Wk = (const float*)d_in[2];
    const float* Wv = (const float*)d_in[3];
    float* outp = (float*)d_out;

    // workspace: Q, K, V each NROWS*HH fp32 (4 MiB each, 12 MiB total)
    float* Qw = (float*)d_ws;
    float* Kw = Qw + (size_t)NROWS * HH;
    float* Vw = Kw + (size_t)NROWS * HH;

    qkv_kernel<<<NROWS / 32, 256, 0, stream>>>(x, Wq, Wk, Wv, Qw, Kw, Vw);
    attn_kernel<<<dim3(TT / 32, BB), 256, 0, stream>>>(Qw, Kw, Vw, outp);
}

// Round 2
// 440.353 us; speedup vs baseline: 1.5038x; 1.5038x over previous
//
#include <hip/hip_runtime.h>
#include <hip/hip_bf16.h>

// Head: B=8, T=2048, D=1024, H=64, fp32 in/out.
#define BB 8
#define TT 2048
#define DD 1024
#define HH 64
#define NROWS (BB*TT)
#define SCALE 45.25483399593904f   // sqrt(2048)

// ---------------------------------------------------------------------------
// Kernel A: QKV projection, fp32 SIMT, W chunk staged in LDS.
// block = 256 threads (4 waves), M-tile = 32 rows, K-chunk = 64.
// Lane decomposition: hq = lane&15 (4 h-cols = float4), g = lane>>4 (row pair).
// Each thread: 2 rows x 4 h x 3 matrices = 24 fp32 accumulators.
// Inner loop per 4 dd: 2 broadcast x b128 + 12 W b128 (4-way bcast) vs 96 FMA.
// ---------------------------------------------------------------------------
#define XSL 17   // x LDS row stride in float4 (padded: 16+1 to break bank alias)

__global__ __launch_bounds__(256) void qkv_kernel(
        const float* __restrict__ x,
        const float* __restrict__ Wq, const float* __restrict__ Wk,
        const float* __restrict__ Wv,
        float* __restrict__ Q, float* __restrict__ K, float* __restrict__ V) {
    __shared__ float xs[32 * XSL * 4];      // 8.5 KiB, [r][17 f4]
    __shared__ float Ws[3 * 64 * 64];       // 48 KiB, [m][dd][h]
    const int tid  = threadIdx.x;
    const int lane = tid & 63;
    const int w    = tid >> 6;
    const int hq   = lane & 15;             // float4 h-group: h = hq*4
    const int g    = lane >> 4;             // 0..3 row-pair group
    const int row0 = blockIdx.x * 32;
    const int r0   = w * 8 + g * 2;         // local row (and r0+1)

    float4* xs4 = (float4*)xs;
    float4* Ws4 = (float4*)Ws;
    const float4* xg = (const float4*)x;    // [row][256]
    const float4* wg0 = (const float4*)Wq;  // [1024][16]
    const float4* wg1 = (const float4*)Wk;
    const float4* wg2 = (const float4*)Wv;

    float4 acc[3][2];
    #pragma unroll
    for (int m = 0; m < 3; ++m)
        #pragma unroll
        for (int r = 0; r < 2; ++r) acc[m][r] = make_float4(0.f, 0.f, 0.f, 0.f);

    for (int c = 0; c < DD / 64; ++c) {     // 16 K-chunks
        __syncthreads();
        // stage x chunk: 32 rows x 16 f4
        #pragma unroll
        for (int p = 0; p < 2; ++p) {
            int i = tid + p * 256;
            int r = i >> 4, q = i & 15;
            xs4[r * XSL + q] = xg[(size_t)(row0 + r) * 256 + c * 16 + q];
        }
        // stage W chunk: 3 x 1024 f4, contiguous in global
        #pragma unroll
        for (int p = 0; p < 4; ++p) {
            int i = tid + p * 256;
            Ws4[i]        = wg0[c * 1024 + i];
            Ws4[1024 + i] = wg1[c * 1024 + i];
            Ws4[2048 + i] = wg2[c * 1024 + i];
        }
        __syncthreads();

        #pragma unroll 4
        for (int q4 = 0; q4 < 16; ++q4) {
            float4 xa = xs4[r0 * XSL + q4];
            float4 xb = xs4[(r0 + 1) * XSL + q4];
            const float xav[4] = {xa.x, xa.y, xa.z, xa.w};
            const float xbv[4] = {xb.x, xb.y, xb.z, xb.w};
            #pragma unroll
            for (int qq = 0; qq < 4; ++qq) {
                const int dd = q4 * 4 + qq;
                float4 w0 = Ws4[dd * 16 + hq];
                float4 w1 = Ws4[1024 + dd * 16 + hq];
                float4 w2 = Ws4[2048 + dd * 16 + hq];
                float a = xav[qq], bvv = xbv[qq];
                acc[0][0].x = fmaf(a, w0.x, acc[0][0].x);
                acc[0][0].y = fmaf(a, w0.y, acc[0][0].y);
                acc[0][0].z = fmaf(a, w0.z, acc[0][0].z);
                acc[0][0].w = fmaf(a, w0.w, acc[0][0].w);
                acc[0][1].x = fmaf(bvv, w0.x, acc[0][1].x);
                acc[0][1].y = fmaf(bvv, w0.y, acc[0][1].y);
                acc[0][1].z = fmaf(bvv, w0.z, acc[0][1].z);
                acc[0][1].w = fmaf(bvv, w0.w, acc[0][1].w);
                acc[1][0].x = fmaf(a, w1.x, acc[1][0].x);
                acc[1][0].y = fmaf(a, w1.y, acc[1][0].y);
                acc[1][0].z = fmaf(a, w1.z, acc[1][0].z);
                acc[1][0].w = fmaf(a, w1.w, acc[1][0].w);
                acc[1][1].x = fmaf(bvv, w1.x, acc[1][1].x);
                acc[1][1].y = fmaf(bvv, w1.y, acc[1][1].y);
                acc[1][1].z = fmaf(bvv, w1.z, acc[1][1].z);
                acc[1][1].w = fmaf(bvv, w1.w, acc[1][1].w);
                acc[2][0].x = fmaf(a, w2.x, acc[2][0].x);
                acc[2][0].y = fmaf(a, w2.y, acc[2][0].y);
                acc[2][0].z = fmaf(a, w2.z, acc[2][0].z);
                acc[2][0].w = fmaf(a, w2.w, acc[2][0].w);
                acc[2][1].x = fmaf(bvv, w2.x, acc[2][1].x);
                acc[2][1].y = fmaf(bvv, w2.y, acc[2][1].y);
                acc[2][1].z = fmaf(bvv, w2.z, acc[2][1].z);
                acc[2][1].w = fmaf(bvv, w2.w, acc[2][1].w);
            }
        }
    }

    const size_t o = (size_t)(row0 + r0) * HH + hq * 4;
    *(float4*)(Q + o)      = acc[0][0];
    *(float4*)(Q + o + HH) = acc[0][1];
    *(float4*)(K + o)      = acc[1][0];
    *(float4*)(K + o + HH) = acc[1][1];
    *(float4*)(V + o)      = acc[2][0];
    *(float4*)(V + o + HH) = acc[2][1];
}

// ---------------------------------------------------------------------------
// Kernel B: causal flash attention, fp32 SIMT.
// block = 128 threads (2 waves), QT=16 rows (8/wave); 1024 blocks, heavy-first.
// 8 lanes per query row each own an 8-dim slice; butterfly shfl for scores.
// K/V tiles (64 keys) staged in LDS (32 KiB -> 5 blocks/CU).
// ---------------------------------------------------------------------------
__global__ __launch_bounds__(128) void attn_kernel(
        const float* __restrict__ Q, const float* __restrict__ K,
        const float* __restrict__ V, float* __restrict__ out) {
    __shared__ float Ks[64 * 64];           // 16 KiB
    __shared__ float Vs[64 * 64];           // 16 KiB
    const int tid  = threadIdx.x;
    const int lane = tid & 63;
    const int w    = tid >> 6;              // wave 0..1
    const int sub  = lane & 7;              // dim-slice owner 0..7
    const int rloc = lane >> 3;             // row-in-wave 0..7
    const int b    = blockIdx.y;
    const int q0   = (gridDim.x - 1 - blockIdx.x) * 16;   // heavy blocks first
    const int t    = q0 + w * 8 + rloc;

    const size_t rowQ = ((size_t)b * TT + t) * HH + sub * 8;
    float4 qa = *(const float4*)(Q + rowQ);
    float4 qb = *(const float4*)(Q + rowQ + 4);

    float4 accA = {0.f, 0.f, 0.f, 0.f};
    float4 accB = {0.f, 0.f, 0.f, 0.f};
    float  m = -1e30f, l = 0.f;

    const int numKT = (q0 + 15) / 64 + 1;

    for (int kt = 0; kt < numKT; ++kt) {
        __syncthreads();
        const float4* kg  = (const float4*)(K + ((size_t)b * TT + kt * 64) * HH);
        const float4* vg  = (const float4*)(V + ((size_t)b * TT + kt * 64) * HH);
        float4* ks4 = (float4*)Ks;
        float4* vs4 = (float4*)Vs;
        #pragma unroll
        for (int p = 0; p < 8; ++p) {
            int i = tid + p * 128;
            ks4[i] = kg[i];
            vs4[i] = vg[i];
        }
        __syncthreads();

        for (int j0 = 0; j0 < 64; j0 += 8) {
            float s[8];
            #pragma unroll
            for (int kk = 0; kk < 8; ++kk) {
                const float4* kp = (const float4*)(Ks + (j0 + kk) * HH + sub * 8);
                float4 ka = kp[0], kb2 = kp[1];
                s[kk] = qa.x * ka.x + qa.y * ka.y + qa.z * ka.z + qa.w * ka.w
                      + qb.x * kb2.x + qb.y * kb2.y + qb.z * kb2.z + qb.w * kb2.w;
            }
            #pragma unroll
            for (int kk = 0; kk < 8; ++kk) {
                s[kk] += __shfl_xor(s[kk], 1);
                s[kk] += __shfl_xor(s[kk], 2);
                s[kk] += __shfl_xor(s[kk], 4);
            }
            const int kbase = kt * 64 + j0;
            float pm = -1e30f;
            #pragma unroll
            for (int kk = 0; kk < 8; ++kk) {
                s[kk] = (kbase + kk <= t) ? s[kk] * SCALE : -1e30f;
                pm = fmaxf(pm, s[kk]);
            }
            if (pm > m) {
                float es = __expf(m - pm);
                m = pm;
                l *= es;
                accA.x *= es; accA.y *= es; accA.z *= es; accA.w *= es;
                accB.x *= es; accB.y *= es; accB.z *= es; accB.w *= es;
            }
            float p[8], ps = 0.f;
            #pragma unroll
            for (int kk = 0; kk < 8; ++kk) {
                p[kk] = __expf(s[kk] - m);
                ps += p[kk];
            }
            l += ps;
            #pragma unroll
            for (int kk = 0; kk < 8; ++kk) {
                const float4* vp = (const float4*)(Vs + (j0 + kk) * HH + sub * 8);
                float4 va = vp[0], vb = vp[1];
                accA.x = fmaf(p[kk], va.x, accA.x);
                accA.y = fmaf(p[kk], va.y, accA.y);
                accA.z = fmaf(p[kk], va.z, accA.z);
                accA.w = fmaf(p[kk], va.w, accA.w);
                accB.x = fmaf(p[kk], vb.x, accB.x);
                accB.y = fmaf(p[kk], vb.y, accB.y);
                accB.z = fmaf(p[kk], vb.z, accB.z);
                accB.w = fmaf(p[kk], vb.w, accB.w);
            }
        }
    }

    const float inv = 1.0f / l;
    float4 oA = {accA.x * inv, accA.y * inv, accA.z * inv, accA.w * inv};
    float4 oB = {accB.x * inv, accB.y * inv, accB.z * inv, accB.w * inv};
    *(float4*)(out + rowQ)     = oA;
    *(float4*)(out + rowQ + 4) = oB;
}

// ---------------------------------------------------------------------------
extern "C" void kernel_launch(void* const* d_in, const int* in_sizes, int n_in,
                              void* d_out, int out_size, void* d_ws, size_t ws_size,
                              hipStream_t stream) {
    const float* x  = (const float*)d_in[0];
    const float* Wq = (const float*)d_in[1];
    const float* Wk = (const float*)d_in[2];
    const float* Wv = (const float*)d_in[3];
    float* outp = (float*)d_out;

    float* Qw = (float*)d_ws;
    float* Kw = Qw + (size_t)NROWS * HH;
    float* Vw = Kw + (size_t)NROWS * HH;

    qkv_kernel<<<NROWS / 32, 256, 0, stream>>>(x, Wq, Wk, Wv, Qw, Kw, Vw);
    attn_kernel<<<dim3(TT / 16, BB), 128, 0, stream>>>(Qw, Kw, Vw, outp);
}

// Round 4
// 164.946 us; speedup vs baseline: 4.0148x; 2.6697x over previous
//
#include <hip/hip_runtime.h>
#include <hip/hip_bf16.h>

// Head: B=8, T=2048, D=1024, H=64, fp32 in/out.
#define BB 8
#define TT 2048
#define DD 1024
#define HH 64
#define NROWS (BB*TT)
#define SCALE 45.25483399593904f   // sqrt(2048)

typedef __attribute__((ext_vector_type(8))) short short8;
typedef __attribute__((ext_vector_type(4))) float f32x4;

__device__ inline ushort bf16rne(float f) {
    unsigned u = __float_as_uint(f);
    return (ushort)((u + 0x7fffu + ((u >> 16) & 1u)) >> 16);
}
__device__ inline void bfsplit(float f, ushort& hi, ushort& lo) {
    hi = bf16rne(f);
    float fh = __uint_as_float(((unsigned)hi) << 16);
    lo = bf16rne(f - fh);
}
__device__ inline float fidx(const float4& v, int i) {
    return i == 0 ? v.x : i == 1 ? v.y : i == 2 ? v.z : v.w;
}

// ---------------------------------------------------------------------------
// Kernel A: QKV projection, fp32 SIMT, W chunk staged in LDS. (round-2 proven)
// Epilogue emits: Q fp32 [row][h]; Khi/Klo bf16 [row][h]; Vt bf16 [b][h][t].
// ---------------------------------------------------------------------------
#define XSL 17

__global__ __launch_bounds__(256) void qkv_kernel(
        const float* __restrict__ x,
        const float* __restrict__ Wq, const float* __restrict__ Wk,
        const float* __restrict__ Wv,
        float* __restrict__ Qo, ushort* __restrict__ KhiP,
        ushort* __restrict__ KloP, ushort* __restrict__ VtP) {
    __shared__ float xs[32 * XSL * 4];
    __shared__ float Ws[3 * 64 * 64];
    const int tid  = threadIdx.x;
    const int lane = tid & 63;
    const int w    = tid >> 6;
    const int hq   = lane & 15;
    const int g    = lane >> 4;
    const int row0 = blockIdx.x * 32;
    const int r0   = w * 8 + g * 2;

    float4* xs4 = (float4*)xs;
    float4* Ws4 = (float4*)Ws;
    const float4* xg  = (const float4*)x;
    const float4* wg0 = (const float4*)Wq;
    const float4* wg1 = (const float4*)Wk;
    const float4* wg2 = (const float4*)Wv;

    float4 acc[3][2];
    #pragma unroll
    for (int m = 0; m < 3; ++m)
        #pragma unroll
        for (int r = 0; r < 2; ++r) acc[m][r] = make_float4(0.f, 0.f, 0.f, 0.f);

    for (int c = 0; c < DD / 64; ++c) {
        __syncthreads();
        #pragma unroll
        for (int p = 0; p < 2; ++p) {
            int i = tid + p * 256;
            int r = i >> 4, q = i & 15;
            xs4[r * XSL + q] = xg[(size_t)(row0 + r) * 256 + c * 16 + q];
        }
        #pragma unroll
        for (int p = 0; p < 4; ++p) {
            int i = tid + p * 256;
            Ws4[i]        = wg0[c * 1024 + i];
            Ws4[1024 + i] = wg1[c * 1024 + i];
            Ws4[2048 + i] = wg2[c * 1024 + i];
        }
        __syncthreads();

        #pragma unroll 4
        for (int q4 = 0; q4 < 16; ++q4) {
            float4 xa = xs4[r0 * XSL + q4];
            float4 xb = xs4[(r0 + 1) * XSL + q4];
            const float xav[4] = {xa.x, xa.y, xa.z, xa.w};
            const float xbv[4] = {xb.x, xb.y, xb.z, xb.w};
            #pragma unroll
            for (int qq = 0; qq < 4; ++qq) {
                const int dd = q4 * 4 + qq;
                float4 w0 = Ws4[dd * 16 + hq];
                float4 w1 = Ws4[1024 + dd * 16 + hq];
                float4 w2 = Ws4[2048 + dd * 16 + hq];
                float a = xav[qq], bvv = xbv[qq];
                acc[0][0].x = fmaf(a, w0.x, acc[0][0].x);
                acc[0][0].y = fmaf(a, w0.y, acc[0][0].y);
                acc[0][0].z = fmaf(a, w0.z, acc[0][0].z);
                acc[0][0].w = fmaf(a, w0.w, acc[0][0].w);
                acc[0][1].x = fmaf(bvv, w0.x, acc[0][1].x);
                acc[0][1].y = fmaf(bvv, w0.y, acc[0][1].y);
                acc[0][1].z = fmaf(bvv, w0.z, acc[0][1].z);
                acc[0][1].w = fmaf(bvv, w0.w, acc[0][1].w);
                acc[1][0].x = fmaf(a, w1.x, acc[1][0].x);
                acc[1][0].y = fmaf(a, w1.y, acc[1][0].y);
                acc[1][0].z = fmaf(a, w1.z, acc[1][0].z);
                acc[1][0].w = fmaf(a, w1.w, acc[1][0].w);
                acc[1][1].x = fmaf(bvv, w1.x, acc[1][1].x);
                acc[1][1].y = fmaf(bvv, w1.y, acc[1][1].y);
                acc[1][1].z = fmaf(bvv, w1.z, acc[1][1].z);
                acc[1][1].w = fmaf(bvv, w1.w, acc[1][1].w);
                acc[2][0].x = fmaf(a, w2.x, acc[2][0].x);
                acc[2][0].y = fmaf(a, w2.y, acc[2][0].y);
                acc[2][0].z = fmaf(a, w2.z, acc[2][0].z);
                acc[2][0].w = fmaf(a, w2.w, acc[2][0].w);
                acc[2][1].x = fmaf(bvv, w2.x, acc[2][1].x);
                acc[2][1].y = fmaf(bvv, w2.y, acc[2][1].y);
                acc[2][1].z = fmaf(bvv, w2.z, acc[2][1].z);
                acc[2][1].w = fmaf(bvv, w2.w, acc[2][1].w);
            }
        }
    }

    const size_t rowg = (size_t)(row0 + r0);
    const int bb = row0 / TT;
    const int tloc = (row0 % TT) + r0;          // even
    *(float4*)(Qo + rowg * HH + hq * 4)       = acc[0][0];
    *(float4*)(Qo + (rowg + 1) * HH + hq * 4) = acc[0][1];
    #pragma unroll
    for (int r = 0; r < 2; ++r) {
        ushort hi[4], lo[4];
        #pragma unroll
        for (int i = 0; i < 4; ++i) bfsplit(fidx(acc[1][r], i), hi[i], lo[i]);
        uint2 hp = make_uint2(hi[0] | ((unsigned)hi[1] << 16), hi[2] | ((unsigned)hi[3] << 16));
        uint2 lp = make_uint2(lo[0] | ((unsigned)lo[1] << 16), lo[2] | ((unsigned)lo[3] << 16));
        *(uint2*)(KhiP + (rowg + r) * HH + hq * 4) = hp;
        *(uint2*)(KloP + (rowg + r) * HH + hq * 4) = lp;
    }
    #pragma unroll
    for (int i = 0; i < 4; ++i) {
        int h = hq * 4 + i;
        unsigned pk = (unsigned)bf16rne(fidx(acc[2][0], i))
                    | ((unsigned)bf16rne(fidx(acc[2][1], i)) << 16);
        *(unsigned*)(VtP + (size_t)(bb * 64 + h) * TT + tloc) = pk;
    }
}

// ---------------------------------------------------------------------------
// Kernel B: causal flash attention via MFMA 16x16x32 bf16, split-precision QK.
// block = 128 (2 waves), QB=32 q-rows (16/wave), KB=64 keys/iter.
// Swapped layout: S^T = mfma(K, Q) -> lane holds 16 keys for q = lane&15.
// Each query row is co-owned by lanes {n, n+16, n+32, n+48}; BOTH the tile max
// AND the exp-sum must be butterfly-reduced across that group (r3 fix: ps).
// ---------------------------------------------------------------------------
__global__ __launch_bounds__(128) void attn_kernel(
        const float* __restrict__ Q, const ushort* __restrict__ Khi,
        const ushort* __restrict__ Klo, const ushort* __restrict__ Vt,
        float* __restrict__ out) {
    __shared__ ushort KhiL[64 * 64];   // [key][h ^ ((key&7)<<3)]
    __shared__ ushort KloL[64 * 64];
    __shared__ ushort VtL[64 * 64];    // [h][key ^ ((h&7)<<3)]
    const int tid  = threadIdx.x;
    const int lane = tid & 63;
    const int w    = tid >> 6;
    const int n    = lane & 15;
    const int g    = lane >> 4;
    const int b    = blockIdx.y;
    const int q0   = ((int)gridDim.x - 1 - (int)blockIdx.x) * 32;  // heavy-first
    const int qmin = q0 + w * 16;
    const int qrow = qmin + n;
    const int csw  = n & 7;

    short8 qhi0, qhi1, qlo0, qlo1;
    {
        const float* qp = Q + ((size_t)b * TT + qrow) * HH + 8 * g;
        float v0[8], v1[8];
        *(float4*)(v0)     = *(const float4*)(qp);
        *(float4*)(v0 + 4) = *(const float4*)(qp + 4);
        *(float4*)(v1)     = *(const float4*)(qp + 32);
        *(float4*)(v1 + 4) = *(const float4*)(qp + 36);
        #pragma unroll
        for (int j = 0; j < 8; ++j) {
            ushort hi, lo;
            bfsplit(v0[j], hi, lo); qhi0[j] = (short)hi; qlo0[j] = (short)lo;
            bfsplit(v1[j], hi, lo); qhi1[j] = (short)hi; qlo1[j] = (short)lo;
        }
    }

    f32x4 accO[4];
    #pragma unroll
    for (int t = 0; t < 4; ++t) accO[t] = (f32x4)0.f;
    float m = -1e30f, l = 0.f;

    const int niter = ((q0 + 31) >> 6) + 1;
    const ushort* gkh = Khi + (size_t)b * TT * HH;
    const ushort* gkl = Klo + (size_t)b * TT * HH;
    const ushort* gvt = Vt + (size_t)b * 64 * TT;

    for (int it = 0; it < niter; ++it) {
        const int kb = it * 64;
        __syncthreads();
        #pragma unroll
        for (int p = 0; p < 4; ++p) {
            int idx = (p << 7) + tid;
            int row = idx >> 3;
            int c   = idx & 7;
            int dst = (row << 6) + (((c ^ (row & 7))) << 3);
            *(int4*)&KhiL[dst] = *(const int4*)(gkh + (size_t)(kb + row) * HH + (c << 3));
            *(int4*)&KloL[dst] = *(const int4*)(gkl + (size_t)(kb + row) * HH + (c << 3));
            *(int4*)&VtL[dst]  = *(const int4*)(gvt + (size_t)row * TT + kb + (c << 3));
        }
        __syncthreads();

        f32x4 s4[4];
        #pragma unroll
        for (int s = 0; s < 4; ++s) {
            const int keyl = 16 * s + n;
            const ushort* kbase = &KhiL[keyl << 6];
            const ushort* lbase = &KloL[keyl << 6];
            short8 kh0 = *(const short8*)(kbase + ((g ^ csw) << 3));
            short8 kh1 = *(const short8*)(kbase + (((4 + g) ^ csw) << 3));
            short8 kl0 = *(const short8*)(lbase + ((g ^ csw) << 3));
            short8 kl1 = *(const short8*)(lbase + (((4 + g) ^ csw) << 3));
            f32x4 a = (f32x4)0.f;
            a = __builtin_amdgcn_mfma_f32_16x16x32_bf16(kh0, qhi0, a, 0, 0, 0);
            a = __builtin_amdgcn_mfma_f32_16x16x32_bf16(kh1, qhi1, a, 0, 0, 0);
            a = __builtin_amdgcn_mfma_f32_16x16x32_bf16(kl0, qhi0, a, 0, 0, 0);
            a = __builtin_amdgcn_mfma_f32_16x16x32_bf16(kl1, qhi1, a, 0, 0, 0);
            a = __builtin_amdgcn_mfma_f32_16x16x32_bf16(kh0, qlo0, a, 0, 0, 0);
            a = __builtin_amdgcn_mfma_f32_16x16x32_bf16(kh1, qlo1, a, 0, 0, 0);
            s4[s] = a;
        }

        float sm[16];
        if (kb + 63 > qmin) {
            #pragma unroll
            for (int s = 0; s < 4; ++s)
                #pragma unroll
                for (int r = 0; r < 4; ++r) {
                    int keyg = kb + 16 * s + 4 * g + r;
                    sm[s * 4 + r] = (keyg <= qrow) ? s4[s][r] * SCALE : -1e30f;
                }
        } else {
            #pragma unroll
            for (int s = 0; s < 4; ++s)
                #pragma unroll
                for (int r = 0; r < 4; ++r) sm[s * 4 + r] = s4[s][r] * SCALE;
        }
        float pm = sm[0];
        #pragma unroll
        for (int i = 1; i < 16; ++i) pm = fmaxf(pm, sm[i]);
        pm = fmaxf(pm, __shfl_xor(pm, 16));
        pm = fmaxf(pm, __shfl_xor(pm, 32));
        float mn = fmaxf(m, pm);
        float es = __expf(m - mn);
        float p[16], ps = 0.f;
        #pragma unroll
        for (int i = 0; i < 16; ++i) { p[i] = __expf(sm[i] - mn); ps += p[i]; }
        // r3 FIX: denominator must cover ALL keys of this query row -> reduce
        // the partial exp-sum across the 4-lane group (was lane-local before;
        // fully-masked lanes had l==0 -> 1/l = inf -> NaN, others l/4).
        ps += __shfl_xor(ps, 16);
        ps += __shfl_xor(ps, 32);
        l = l * es + ps;
        m = mn;
        #pragma unroll
        for (int t = 0; t < 4; ++t)
            #pragma unroll
            for (int r = 0; r < 4; ++r) accO[t][r] *= es;

        short8 pf0, pf1;
        #pragma unroll
        for (int j = 0; j < 4; ++j) {
            pf0[j]     = (short)bf16rne(p[0 * 4 + j]);
            pf0[j + 4] = (short)bf16rne(p[1 * 4 + j]);
            pf1[j]     = (short)bf16rne(p[2 * 4 + j]);
            pf1[j + 4] = (short)bf16rne(p[3 * 4 + j]);
        }

        #pragma unroll
        for (int t = 0; t < 4; ++t) {
            const int h = 16 * t + n;
            const ushort* vb = &VtL[h << 6];
            union { int2 d[2]; short8 v; } u0, u1;
            u0.d[0] = *(const int2*)(vb + ((4 * g) ^ (csw << 3)));
            u0.d[1] = *(const int2*)(vb + ((16 + 4 * g) ^ (csw << 3)));
            u1.d[0] = *(const int2*)(vb + ((32 + 4 * g) ^ (csw << 3)));
            u1.d[1] = *(const int2*)(vb + ((48 + 4 * g) ^ (csw << 3)));
            accO[t] = __builtin_amdgcn_mfma_f32_16x16x32_bf16(u0.v, pf0, accO[t], 0, 0, 0);
            accO[t] = __builtin_amdgcn_mfma_f32_16x16x32_bf16(u1.v, pf1, accO[t], 0, 0, 0);
        }
    }

    const float inv = 1.0f / l;
    float* op = out + ((size_t)b * TT + qrow) * HH + 4 * g;
    #pragma unroll
    for (int t = 0; t < 4; ++t) {
        float4 o = make_float4(accO[t][0] * inv, accO[t][1] * inv,
                               accO[t][2] * inv, accO[t][3] * inv);
        *(float4*)(op + 16 * t) = o;
    }
}

// ---------------------------------------------------------------------------
extern "C" void kernel_launch(void* const* d_in, const int* in_sizes, int n_in,
                              void* d_out, int out_size, void* d_ws, size_t ws_size,
                              hipStream_t stream) {
    const float* x  = (const float*)d_in[0];
    const float* Wq = (const float*)d_in[1];
    const float* Wk = (const float*)d_in[2];
    const float* Wv = (const float*)d_in[3];
    float* outp = (float*)d_out;

    float*  Qw   = (float*)d_ws;
    ushort* KhiP = (ushort*)(Qw + (size_t)NROWS * HH);
    ushort* KloP = KhiP + (size_t)NROWS * HH;
    ushort* VtP  = KloP + (size_t)NROWS * HH;

    qkv_kernel<<<NROWS / 32, 256, 0, stream>>>(x, Wq, Wk, Wv, Qw, KhiP, KloP, VtP);
    attn_kernel<<<dim3(TT / 32, BB), 128, 0, stream>>>(Qw, KhiP, KloP, VtP, outp);
}

// Round 5
// 98.043 us; speedup vs baseline: 6.7544x; 1.6824x over previous
//
#include <hip/hip_runtime.h>
#include <hip/hip_bf16.h>

// Head: B=8, T=2048, D=1024, H=64, fp32 in/out.
#define BB 8
#define TT 2048
#define DD 1024
#define HH 64
#define NROWS (BB*TT)
#define SCALE 45.25483399593904f   // sqrt(2048)

typedef __attribute__((ext_vector_type(8))) short short8;
typedef __attribute__((ext_vector_type(4))) float f32x4;

__device__ inline ushort bf16rne(float f) {
    unsigned u = __float_as_uint(f);
    return (ushort)((u + 0x7fffu + ((u >> 16) & 1u)) >> 16);
}
__device__ inline void bfsplit(float f, ushort& hi, ushort& lo) {
    hi = bf16rne(f);
    float fh = __uint_as_float(((unsigned)hi) << 16);
    lo = bf16rne(f - fh);
}
__device__ inline void split_pack8(const float* v, int4& h4, int4& l4) {
    ushort h[8], l[8];
    #pragma unroll
    for (int j = 0; j < 8; ++j) bfsplit(v[j], h[j], l[j]);
    h4 = make_int4((int)(h[0] | ((unsigned)h[1] << 16)), (int)(h[2] | ((unsigned)h[3] << 16)),
                   (int)(h[4] | ((unsigned)h[5] << 16)), (int)(h[6] | ((unsigned)h[7] << 16)));
    l4 = make_int4((int)(l[0] | ((unsigned)l[1] << 16)), (int)(l[2] | ((unsigned)l[3] << 16)),
                   (int)(l[4] | ((unsigned)l[5] << 16)), (int)(l[6] | ((unsigned)l[7] << 16)));
}

// ---------------------------------------------------------------------------
// Kernel P: W prep. Transpose W[k][n] -> Wt[n][k], split to bf16 hi/lo, and
// emit PRE-SWIZZLED chunk-major layout so the GEMM's B-stage is a linear copy:
//   Wp[c][nglob][g8][j] = bf16(W_mat[c*64 + ((g8^(nglob&7))*8)+j][nglob&63])
// ---------------------------------------------------------------------------
__global__ __launch_bounds__(256) void wprep_kernel(
        const float* __restrict__ Wq, const float* __restrict__ Wk,
        const float* __restrict__ Wv,
        ushort* __restrict__ WpHi, ushort* __restrict__ WpLo) {
    __shared__ float ws[64 * 65];
    const int m = blockIdx.x >> 4;      // matrix 0..2
    const int c = blockIdx.x & 15;      // k-chunk 0..15
    const float* W = (m == 0) ? Wq : (m == 1) ? Wk : Wv;
    const int tid = threadIdx.x;

    #pragma unroll
    for (int p = 0; p < 4; ++p) {
        int i = tid + p * 256;          // 0..1023 float4 units
        int r = i >> 4, q4 = i & 15;
        float4 v = *(const float4*)(W + (size_t)(c * 64 + r) * 64 + q4 * 4);
        ws[r * 65 + q4 * 4 + 0] = v.x;
        ws[r * 65 + q4 * 4 + 1] = v.y;
        ws[r * 65 + q4 * 4 + 2] = v.z;
        ws[r * 65 + q4 * 4 + 3] = v.w;
    }
    __syncthreads();

    #pragma unroll
    for (int p = 0; p < 2; ++p) {
        int gi = tid + p * 256;         // 0..511
        int nn = gi >> 3, g8 = gi & 7;
        int o  = g8 ^ (nn & 7);
        float v[8];
        #pragma unroll
        for (int j = 0; j < 8; ++j) v[j] = ws[(o * 8 + j) * 65 + nn];
        int4 h4, l4; split_pack8(v, h4, l4);
        size_t base = (size_t)c * 12288 + (size_t)(m * 64 + nn) * 64 + g8 * 8;
        *(int4*)(WpHi + base) = h4;
        *(int4*)(WpLo + base) = l4;
    }
}

// ---------------------------------------------------------------------------
// Kernel A: QKV projection via MFMA 16x16x32 bf16, 3-pass split precision.
// C[16384 x 192] = x[16384 x 1024] @ [Wq|Wk|Wv].
// block = 256 (4 waves), BM=64, BK=64; waves n-split (48 cols each, 3 n-tiles
// x 4 m-subtiles). XOR-octet LDS swizzle on A and B (2-way max = free).
// Epilogue: Q fp32 [row][h]; Khi/Klo bf16 [row][h]; Vt bf16 [b][h][t].
// ---------------------------------------------------------------------------
__global__ __launch_bounds__(256) void qkv_kernel(
        const float* __restrict__ x,
        const ushort* __restrict__ WpHi, const ushort* __restrict__ WpLo,
        float* __restrict__ Qo, ushort* __restrict__ KhiP,
        ushort* __restrict__ KloP, ushort* __restrict__ VtP) {
    __shared__ ushort Ahi[64 * 64], Alo[64 * 64];     // 8 KiB each
    __shared__ ushort Bhi[192 * 64], Blo[192 * 64];   // 24 KiB each
    const int tid  = threadIdx.x;
    const int lane = tid & 63;
    const int w    = tid >> 6;
    const int n15  = lane & 15;
    const int g    = lane >> 4;
    const int csw  = n15 & 7;
    const int row0 = blockIdx.x * 64;

    f32x4 acc[4][3];
    #pragma unroll
    for (int ms = 0; ms < 4; ++ms)
        #pragma unroll
        for (int nt = 0; nt < 3; ++nt) acc[ms][nt] = (f32x4)0.f;

    for (int c = 0; c < 16; ++c) {
        __syncthreads();
        // ---- stage A: x rows -> bf16 hi/lo, swizzled ----
        #pragma unroll
        for (int p = 0; p < 2; ++p) {
            int gi = tid + p * 256;     // 0..511
            int r = gi >> 3, oc = gi & 7;
            const float* src = x + (size_t)(row0 + r) * 1024 + c * 64 + oc * 8;
            float v[8];
            *(float4*)v       = *(const float4*)src;
            *(float4*)(v + 4) = *(const float4*)(src + 4);
            int4 h4, l4; split_pack8(v, h4, l4);
            int di = r * 64 + ((oc ^ (r & 7)) << 3);
            *(int4*)&Ahi[di] = h4;
            *(int4*)&Alo[di] = l4;
        }
        // ---- stage B: pre-swizzled in global -> pure linear copy ----
        {
            const int4* sh = (const int4*)(WpHi + (size_t)c * 12288);
            const int4* sl = (const int4*)(WpLo + (size_t)c * 12288);
            int4* dh = (int4*)Bhi;
            int4* dl = (int4*)Blo;
            #pragma unroll
            for (int p = 0; p < 6; ++p) {
                int gi = tid + p * 256;  // 0..1535 int4 units
                dh[gi] = sh[gi];
                dl[gi] = sl[gi];
            }
        }
        __syncthreads();

        #pragma unroll
        for (int kh = 0; kh < 2; ++kh) {
            short8 afh[4], afl[4], bfh[3], bfl[3];
            #pragma unroll
            for (int ms = 0; ms < 4; ++ms) {
                int ridx = (ms * 16 + n15) * 64 + (((4 * kh + g) ^ csw) << 3);
                afh[ms] = *(const short8*)&Ahi[ridx];
                afl[ms] = *(const short8*)&Alo[ridx];
            }
            #pragma unroll
            for (int nt = 0; nt < 3; ++nt) {
                int nr = w * 48 + nt * 16 + n15;
                int ridx = nr * 64 + (((4 * kh + g) ^ csw) << 3);
                bfh[nt] = *(const short8*)&Bhi[ridx];
                bfl[nt] = *(const short8*)&Blo[ridx];
            }
            #pragma unroll
            for (int nt = 0; nt < 3; ++nt)
                #pragma unroll
                for (int ms = 0; ms < 4; ++ms) {
                    acc[ms][nt] = __builtin_amdgcn_mfma_f32_16x16x32_bf16(
                        afh[ms], bfh[nt], acc[ms][nt], 0, 0, 0);
                    acc[ms][nt] = __builtin_amdgcn_mfma_f32_16x16x32_bf16(
                        afl[ms], bfh[nt], acc[ms][nt], 0, 0, 0);
                    acc[ms][nt] = __builtin_amdgcn_mfma_f32_16x16x32_bf16(
                        afh[ms], bfl[nt], acc[ms][nt], 0, 0, 0);
                }
        }
    }

    // ---- epilogue: D[m][n] with m = row0+ms*16+4g+r, n = w*48+nt*16+n15 ----
    const int b  = row0 >> 11;
    const int t0 = row0 & 2047;
    #pragma unroll
    for (int nt = 0; nt < 3; ++nt) {
        const int nglob = w * 48 + nt * 16 + n15;
        const int mat = nglob >> 6;     // wave-uniform (16 | 64)
        const int h = nglob & 63;
        #pragma unroll
        for (int ms = 0; ms < 4; ++ms) {
            const int mb = row0 + ms * 16 + 4 * g;
            if (mat == 0) {
                #pragma unroll
                for (int r = 0; r < 4; ++r)
                    Qo[(size_t)(mb + r) * 64 + h] = acc[ms][nt][r];
            } else if (mat == 1) {
                #pragma unroll
                for (int r = 0; r < 4; ++r) {
                    ushort hi, lo; bfsplit(acc[ms][nt][r], hi, lo);
                    KhiP[(size_t)(mb + r) * 64 + h] = hi;
                    KloP[(size_t)(mb + r) * 64 + h] = lo;
                }
            } else {
                ushort pk[4];
                #pragma unroll
                for (int r = 0; r < 4; ++r) pk[r] = bf16rne(acc[ms][nt][r]);
                const int tloc = t0 + ms * 16 + 4 * g;
                *(uint2*)&VtP[((size_t)(b * 64 + h)) * 2048 + tloc] =
                    make_uint2(pk[0] | ((unsigned)pk[1] << 16),
                               pk[2] | ((unsigned)pk[3] << 16));
            }
        }
    }
}

// ---------------------------------------------------------------------------
// Kernel B: causal flash attention via MFMA 16x16x32 bf16 (r4, unchanged).
// ---------------------------------------------------------------------------
__global__ __launch_bounds__(128) void attn_kernel(
        const float* __restrict__ Q, const ushort* __restrict__ Khi,
        const ushort* __restrict__ Klo, const ushort* __restrict__ Vt,
        float* __restrict__ out) {
    __shared__ ushort KhiL[64 * 64];   // [key][h ^ ((key&7)<<3)]
    __shared__ ushort KloL[64 * 64];
    __shared__ ushort VtL[64 * 64];    // [h][key ^ ((h&7)<<3)]
    const int tid  = threadIdx.x;
    const int lane = tid & 63;
    const int w    = tid >> 6;
    const int n    = lane & 15;
    const int g    = lane >> 4;
    const int b    = blockIdx.y;
    const int q0   = ((int)gridDim.x - 1 - (int)blockIdx.x) * 32;  // heavy-first
    const int qmin = q0 + w * 16;
    const int qrow = qmin + n;
    const int csw  = n & 7;

    short8 qhi0, qhi1, qlo0, qlo1;
    {
        const float* qp = Q + ((size_t)b * TT + qrow) * HH + 8 * g;
        float v0[8], v1[8];
        *(float4*)(v0)     = *(const float4*)(qp);
        *(float4*)(v0 + 4) = *(const float4*)(qp + 4);
        *(float4*)(v1)     = *(const float4*)(qp + 32);
        *(float4*)(v1 + 4) = *(const float4*)(qp + 36);
        #pragma unroll
        for (int j = 0; j < 8; ++j) {
            ushort hi, lo;
            bfsplit(v0[j], hi, lo); qhi0[j] = (short)hi; qlo0[j] = (short)lo;
            bfsplit(v1[j], hi, lo); qhi1[j] = (short)hi; qlo1[j] = (short)lo;
        }
    }

    f32x4 accO[4];
    #pragma unroll
    for (int t = 0; t < 4; ++t) accO[t] = (f32x4)0.f;
    float m = -1e30f, l = 0.f;

    const int niter = ((q0 + 31) >> 6) + 1;
    const ushort* gkh = Khi + (size_t)b * TT * HH;
    const ushort* gkl = Klo + (size_t)b * TT * HH;
    const ushort* gvt = Vt + (size_t)b * 64 * TT;

    for (int it = 0; it < niter; ++it) {
        const int kb = it * 64;
        __syncthreads();
        #pragma unroll
        for (int p = 0; p < 4; ++p) {
            int idx = (p << 7) + tid;
            int row = idx >> 3;
            int c   = idx & 7;
            int dst = (row << 6) + (((c ^ (row & 7))) << 3);
            *(int4*)&KhiL[dst] = *(const int4*)(gkh + (size_t)(kb + row) * HH + (c << 3));
            *(int4*)&KloL[dst] = *(const int4*)(gkl + (size_t)(kb + row) * HH + (c << 3));
            *(int4*)&VtL[dst]  = *(const int4*)(gvt + (size_t)row * TT + kb + (c << 3));
        }
        __syncthreads();

        f32x4 s4[4];
        #pragma unroll
        for (int s = 0; s < 4; ++s) {
            const int keyl = 16 * s + n;
            const ushort* kbase = &KhiL[keyl << 6];
            const ushort* lbase = &KloL[keyl << 6];
            short8 kh0 = *(const short8*)(kbase + ((g ^ csw) << 3));
            short8 kh1 = *(const short8*)(kbase + (((4 + g) ^ csw) << 3));
            short8 kl0 = *(const short8*)(lbase + ((g ^ csw) << 3));
            short8 kl1 = *(const short8*)(lbase + (((4 + g) ^ csw) << 3));
            f32x4 a = (f32x4)0.f;
            a = __builtin_amdgcn_mfma_f32_16x16x32_bf16(kh0, qhi0, a, 0, 0, 0);
            a = __builtin_amdgcn_mfma_f32_16x16x32_bf16(kh1, qhi1, a, 0, 0, 0);
            a = __builtin_amdgcn_mfma_f32_16x16x32_bf16(kl0, qhi0, a, 0, 0, 0);
            a = __builtin_amdgcn_mfma_f32_16x16x32_bf16(kl1, qhi1, a, 0, 0, 0);
            a = __builtin_amdgcn_mfma_f32_16x16x32_bf16(kh0, qlo0, a, 0, 0, 0);
            a = __builtin_amdgcn_mfma_f32_16x16x32_bf16(kh1, qlo1, a, 0, 0, 0);
            s4[s] = a;
        }

        float sm[16];
        if (kb + 63 > qmin) {
            #pragma unroll
            for (int s = 0; s < 4; ++s)
                #pragma unroll
                for (int r = 0; r < 4; ++r) {
                    int keyg = kb + 16 * s + 4 * g + r;
                    sm[s * 4 + r] = (keyg <= qrow) ? s4[s][r] * SCALE : -1e30f;
                }
        } else {
            #pragma unroll
            for (int s = 0; s < 4; ++s)
                #pragma unroll
                for (int r = 0; r < 4; ++r) sm[s * 4 + r] = s4[s][r] * SCALE;
        }
        float pm = sm[0];
        #pragma unroll
        for (int i = 1; i < 16; ++i) pm = fmaxf(pm, sm[i]);
        pm = fmaxf(pm, __shfl_xor(pm, 16));
        pm = fmaxf(pm, __shfl_xor(pm, 32));
        float mn = fmaxf(m, pm);
        float es = __expf(m - mn);
        float p[16], ps = 0.f;
        #pragma unroll
        for (int i = 0; i < 16; ++i) { p[i] = __expf(sm[i] - mn); ps += p[i]; }
        ps += __shfl_xor(ps, 16);
        ps += __shfl_xor(ps, 32);
        l = l * es + ps;
        m = mn;
        #pragma unroll
        for (int t = 0; t < 4; ++t)
            #pragma unroll
            for (int r = 0; r < 4; ++r) accO[t][r] *= es;

        short8 pf0, pf1;
        #pragma unroll
        for (int j = 0; j < 4; ++j) {
            pf0[j]     = (short)bf16rne(p[0 * 4 + j]);
            pf0[j + 4] = (short)bf16rne(p[1 * 4 + j]);
            pf1[j]     = (short)bf16rne(p[2 * 4 + j]);
            pf1[j + 4] = (short)bf16rne(p[3 * 4 + j]);
        }

        #pragma unroll
        for (int t = 0; t < 4; ++t) {
            const int h = 16 * t + n;
            const ushort* vb = &VtL[h << 6];
            union { int2 d[2]; short8 v; } u0, u1;
            u0.d[0] = *(const int2*)(vb + ((4 * g) ^ (csw << 3)));
            u0.d[1] = *(const int2*)(vb + ((16 + 4 * g) ^ (csw << 3)));
            u1.d[0] = *(const int2*)(vb + ((32 + 4 * g) ^ (csw << 3)));
            u1.d[1] = *(const int2*)(vb + ((48 + 4 * g) ^ (csw << 3)));
            accO[t] = __builtin_amdgcn_mfma_f32_16x16x32_bf16(u0.v, pf0, accO[t], 0, 0, 0);
            accO[t] = __builtin_amdgcn_mfma_f32_16x16x32_bf16(u1.v, pf1, accO[t], 0, 0, 0);
        }
    }

    const float inv = 1.0f / l;
    float* op = out + ((size_t)b * TT + qrow) * HH + 4 * g;
    #pragma unroll
    for (int t = 0; t < 4; ++t) {
        float4 o = make_float4(accO[t][0] * inv, accO[t][1] * inv,
                               accO[t][2] * inv, accO[t][3] * inv);
        *(float4*)(op + 16 * t) = o;
    }
}

// ---------------------------------------------------------------------------
extern "C" void kernel_launch(void* const* d_in, const int* in_sizes, int n_in,
                              void* d_out, int out_size, void* d_ws, size_t ws_size,
                              hipStream_t stream) {
    const float* x  = (const float*)d_in[0];
    const float* Wq = (const float*)d_in[1];
    const float* Wk = (const float*)d_in[2];
    const float* Wv = (const float*)d_in[3];
    float* outp = (float*)d_out;

    float*  Qw   = (float*)d_ws;                        // 4 MB
    ushort* KhiP = (ushort*)(Qw + (size_t)NROWS * HH);  // 2 MB
    ushort* KloP = KhiP + (size_t)NROWS * HH;           // 2 MB
    ushort* VtP  = KloP + (size_t)NROWS * HH;           // 2 MB
    ushort* WpHi = VtP + (size_t)NROWS * HH;            // 384 KB
    ushort* WpLo = WpHi + (size_t)3 * 64 * 1024;        // 384 KB

    wprep_kernel<<<48, 256, 0, stream>>>(Wq, Wk, Wv, WpHi, WpLo);
    qkv_kernel<<<NROWS / 64, 256, 0, stream>>>(x, WpHi, WpLo, Qw, KhiP, KloP, VtP);
    attn_kernel<<<dim3(TT / 32, BB), 128, 0, stream>>>(Qw, KhiP, KloP, VtP, outp);
}